// Round 1
// baseline (252.247 us; speedup 1.0000x reference)
//
#include <hip/hip_runtime.h>
#include <math.h>

#define N_PTR 2048
#define M_NU  4096
#define DIM   512
#define KCLS  1000

static constexpr float LAMBDA_ = 0.1f;
static constexpr float EPSILON_ = 0.5f;
static constexpr float EPS_ = 1e-8f;

// ---------- block reduction helpers (blockDim.x == 256) ----------
__device__ __forceinline__ float blk_reduce_sum(float v, float* red) {
  #pragma unroll
  for (int off = 32; off > 0; off >>= 1) v += __shfl_down(v, off);
  __syncthreads();
  if ((threadIdx.x & 63) == 0) red[threadIdx.x >> 6] = v;
  __syncthreads();
  return red[0] + red[1] + red[2] + red[3];
}

__device__ __forceinline__ float blk_reduce_max(float v, float* red) {
  #pragma unroll
  for (int off = 32; off > 0; off >>= 1) v = fmaxf(v, __shfl_down(v, off));
  __syncthreads();
  if ((threadIdx.x & 63) == 0) red[threadIdx.x >> 6] = v;
  __syncthreads();
  return fmaxf(fmaxf(red[0], red[1]), fmaxf(red[2], red[3]));
}

// ---------- 1. inverse row norms: invnorm[r] = 1/max(||X[r]||, EPS) ----------
__global__ __launch_bounds__(256) void rownorm_kernel(const float* __restrict__ X,
                                                      float* __restrict__ invnorm,
                                                      int rows, int cols) {
  int gid = blockIdx.x * blockDim.x + threadIdx.x;
  int wave = gid >> 6;
  int lane = gid & 63;
  if (wave >= rows) return;
  const float* row = X + (size_t)wave * cols;
  float s = 0.f;
  for (int c = lane; c < cols; c += 64) { float v = row[c]; s = fmaf(v, v, s); }
  #pragma unroll
  for (int off = 32; off > 0; off >>= 1) s += __shfl_down(s, off);
  if (lane == 0) invnorm[wave] = 1.0f / fmaxf(sqrtf(s), EPS_);
}

// ---------- 2. per-row CE loss: loss = logsumexp(x) - x[label] ----------
__global__ __launch_bounds__(256) void celoss_kernel(const float* __restrict__ logits,
                                                     const int* __restrict__ labels,
                                                     float* __restrict__ losses) {
  __shared__ float red[4];
  int row = blockIdx.x;
  int tid = threadIdx.x;
  const float* x = logits + (size_t)row * KCLS;
  float mx_loc = -INFINITY;
  for (int c = tid; c < KCLS; c += 256) mx_loc = fmaxf(mx_loc, x[c]);
  float mx = blk_reduce_max(mx_loc, red);
  float se_loc = 0.f;
  for (int c = tid; c < KCLS; c += 256) se_loc += expf(x[c] - mx);
  float se = blk_reduce_sum(se_loc, red);
  if (tid == 0) losses[row] = mx + logf(se) - x[labels[row]];
}

// ---------- 3. C[i][j] = (sum_d A[i][d]*B[j][d]) * invA[i] * invB[j] ----------
// 64x64 tile, BK=16, 4x4 per thread, f32.
__global__ __launch_bounds__(256) void gemm_nt_kernel(const float* __restrict__ A,
                                                      const float* __restrict__ B,
                                                      const float* __restrict__ invA,
                                                      const float* __restrict__ invB,
                                                      float* __restrict__ C,
                                                      int rowsA, int rowsB, int ldc) {
  __shared__ float As[16][68];
  __shared__ float Bs[16][68];
  int bi = blockIdx.y * 64;
  int bj = blockIdx.x * 64;
  int tid = threadIdx.x;
  int tx = tid & 15, ty = tid >> 4;
  int lr = tid >> 2;          // 0..63: row within tile for staging
  int lk = (tid & 3) * 4;     // 0,4,8,12: k-quad for staging
  float acc[4][4] = {};
  for (int k0 = 0; k0 < DIM; k0 += 16) {
    {
      int row = bi + lr;
      float4 v = make_float4(0.f, 0.f, 0.f, 0.f);
      if (row < rowsA) v = *reinterpret_cast<const float4*>(&A[(size_t)row * DIM + k0 + lk]);
      As[lk + 0][lr] = v.x; As[lk + 1][lr] = v.y; As[lk + 2][lr] = v.z; As[lk + 3][lr] = v.w;
    }
    {
      int row = bj + lr;
      float4 v = make_float4(0.f, 0.f, 0.f, 0.f);
      if (row < rowsB) v = *reinterpret_cast<const float4*>(&B[(size_t)row * DIM + k0 + lk]);
      Bs[lk + 0][lr] = v.x; Bs[lk + 1][lr] = v.y; Bs[lk + 2][lr] = v.z; Bs[lk + 3][lr] = v.w;
    }
    __syncthreads();
    #pragma unroll
    for (int k = 0; k < 16; ++k) {
      float4 a4 = *reinterpret_cast<const float4*>(&As[k][ty * 4]);
      float4 b4 = *reinterpret_cast<const float4*>(&Bs[k][tx * 4]);
      float av[4] = {a4.x, a4.y, a4.z, a4.w};
      float bv[4] = {b4.x, b4.y, b4.z, b4.w};
      #pragma unroll
      for (int i = 0; i < 4; ++i)
        #pragma unroll
        for (int j = 0; j < 4; ++j)
          acc[i][j] = fmaf(av[i], bv[j], acc[i][j]);
    }
    __syncthreads();
  }
  #pragma unroll
  for (int i = 0; i < 4; ++i) {
    int row = bi + ty * 4 + i;
    if (row >= rowsA) continue;
    float ia = invA[row];
    #pragma unroll
    for (int j = 0; j < 4; ++j) {
      int col = bj + tx * 4 + j;
      if (col < rowsB) C[(size_t)row * ldc + col] = acc[i][j] * ia * invB[col];
    }
  }
}

// ---------- 4. phase A: per-n row max / sumexp + cos-sum partials ----------
__global__ __launch_bounds__(256) void rowpass_kernel(const float* __restrict__ S,
    const float* __restrict__ G, const int* __restrict__ pl, const int* __restrict__ nl,
    const float* __restrict__ nu_loss, float* __restrict__ row_max,
    float* __restrict__ row_sum, float* __restrict__ s_sum, float* __restrict__ gy_sum) {
  __shared__ float e_row[M_NU];   // 16 KB
  __shared__ float red[4];
  int n = blockIdx.x;
  int tid = threadIdx.x;
  const float* Srow = S + (size_t)n * M_NU;
  const float* Grow = G + (size_t)pl[n] * KCLS;
  const float inv_denom = 1.0f / (LAMBDA_ * EPSILON_ + EPS_);
  float loc_s = 0.f, loc_gy = 0.f, loc_max = -INFINITY;
  for (int m = tid; m < M_NU; m += 256) {
    float s = Srow[m];
    float gy = Grow[nl[m]];
    float c = (1.f - s) + (1.f - gy);
    float e = (nu_loss[m] - LAMBDA_ * c) * inv_denom;
    e_row[m] = e;
    loc_s += s; loc_gy += gy;
    loc_max = fmaxf(loc_max, e);
  }
  float rmax = blk_reduce_max(loc_max, red);
  float loc_w = 0.f;
  for (int m = tid; m < M_NU; m += 256) loc_w += expf(e_row[m] - rmax);
  float wsum = blk_reduce_sum(loc_w, red);
  float stot = blk_reduce_sum(loc_s, red);
  float gtot = blk_reduce_sum(loc_gy, red);
  if (tid == 0) {
    row_max[n] = rmax;
    row_sum[n] = wsum;
    s_sum[n] = stot;
    gy_sum[n] = gtot;
  }
}

// ---------- 5. phase B: per-m column sums of weights (no atomics) ----------
__global__ __launch_bounds__(256) void colpass_kernel(const float* __restrict__ S,
    const float* __restrict__ G, const int* __restrict__ pl, const int* __restrict__ nl,
    const float* __restrict__ nu_loss, const float* __restrict__ row_max,
    const float* __restrict__ row_sum, float* __restrict__ partial) {
  int m = blockIdx.x * 256 + threadIdx.x;     // grid.x = M/256
  int chunk = blockIdx.y;                     // 16 chunks of 128 rows
  const int rows_per_chunk = N_PTR / 16;
  int n0 = chunk * rows_per_chunk;
  const float inv_denom = 1.0f / (LAMBDA_ * EPSILON_ + EPS_);
  int nlm = nl[m];
  float lm = nu_loss[m];
  float acc = 0.f;
  for (int n = n0; n < n0 + rows_per_chunk; ++n) {
    float s = S[(size_t)n * M_NU + m];
    float gy = G[(size_t)pl[n] * KCLS + nlm];
    float c = (1.f - s) + (1.f - gy);
    float e = (lm - LAMBDA_ * c) * inv_denom;
    acc += expf(e - row_max[n]) / (row_sum[n] + EPS_);
  }
  partial[(size_t)chunk * M_NU + m] = acc;
}

// ---------- 6. finalize: probs, dro_loss, means ----------
__global__ __launch_bounds__(256) void final_kernel(const float* __restrict__ partial,
    const float* __restrict__ nu_loss, const float* __restrict__ s_sum,
    const float* __restrict__ gy_sum, float* __restrict__ out) {
  __shared__ float red[4];
  int tid = threadIdx.x;
  float locT = 0.f;
  for (int m = tid; m < M_NU; m += 256) {
    float t = 0.f;
    #pragma unroll
    for (int c = 0; c < 16; ++c) t += partial[(size_t)c * M_NU + m];
    out[2 + m] = t;            // raw sum over n, rescaled below
    locT += t;
  }
  float T = blk_reduce_sum(locT, red);
  // probs_pre[m] = raw[m]/N ; p[m] = probs_pre[m] / (sum(probs_pre) + EPS)
  float scale = (1.0f / (float)N_PTR) / (T / (float)N_PTR + EPS_);
  float locD = 0.f;
  for (int m = tid; m < M_NU; m += 256) {
    float p = out[2 + m] * scale;
    out[2 + m] = p;
    locD += p * nu_loss[m];
  }
  float dro = blk_reduce_sum(locD, red);
  float locS = 0.f, locG = 0.f;
  for (int n = tid; n < N_PTR; n += 256) { locS += s_sum[n]; locG += gy_sum[n]; }
  float Stot = blk_reduce_sum(locS, red);
  float Gtot = blk_reduce_sum(locG, red);
  if (tid == 0) {
    const float invNM = 1.0f / ((float)N_PTR * (float)M_NU);
    float mcx = 1.f - Stot * invNM;
    float mcy = 1.f - Gtot * invNM;
    out[0] = dro;              // total_loss (semantic part is 0)
    out[1] = dro;              // dro_loss
    out[2 + M_NU] = mcx + mcy; // mean(C_total)
    out[3 + M_NU] = mcx;       // mean(C_X)
    out[4 + M_NU] = mcy;       // mean(C_Y)
  }
}

extern "C" void kernel_launch(void* const* d_in, const int* in_sizes, int n_in,
                              void* d_out, int out_size, void* d_ws, size_t ws_size,
                              hipStream_t stream) {
  const float* ptr_feat = (const float*)d_in[0];
  // d_in[1] = ptr_logits: unused by the reference
  const int*   ptr_lab  = (const int*)d_in[2];
  const float* nu_feat  = (const float*)d_in[3];
  const float* nu_log   = (const float*)d_in[4];
  const int*   nu_lab   = (const int*)d_in[5];
  const float* cls_w    = (const float*)d_in[6];
  float* out = (float*)d_out;

  float* ws = (float*)d_ws;
  float* S        = ws;                              // N*M        = 8388608 f
  float* G        = S + (size_t)N_PTR * M_NU;        // K*K        = 1000000 f
  float* inv_ptr  = G + (size_t)KCLS * KCLS;         // 2048
  float* inv_nu   = inv_ptr + N_PTR;                 // 4096
  float* inv_cls  = inv_nu + M_NU;                   // 1024 (pad)
  float* nloss    = inv_cls + 1024;                  // 4096
  float* row_max  = nloss + M_NU;                    // 2048
  float* row_sum  = row_max + N_PTR;                 // 2048
  float* s_sum    = row_sum + N_PTR;                 // 2048
  float* gy_sum   = s_sum + N_PTR;                   // 2048
  float* partial  = gy_sum + N_PTR;                  // 16*M = 65536
  // total ~ 37.9 MB of ws

  rownorm_kernel<<<dim3((N_PTR * 64) / 256), 256, 0, stream>>>(ptr_feat, inv_ptr, N_PTR, DIM);
  rownorm_kernel<<<dim3((M_NU * 64) / 256), 256, 0, stream>>>(nu_feat, inv_nu, M_NU, DIM);
  rownorm_kernel<<<dim3((KCLS * 64 + 255) / 256), 256, 0, stream>>>(cls_w, inv_cls, KCLS, DIM);
  celoss_kernel<<<dim3(M_NU), 256, 0, stream>>>(nu_log, nu_lab, nloss);
  gemm_nt_kernel<<<dim3(M_NU / 64, N_PTR / 64), 256, 0, stream>>>(
      ptr_feat, nu_feat, inv_ptr, inv_nu, S, N_PTR, M_NU, M_NU);
  gemm_nt_kernel<<<dim3((KCLS + 63) / 64, (KCLS + 63) / 64), 256, 0, stream>>>(
      cls_w, cls_w, inv_cls, inv_cls, G, KCLS, KCLS, KCLS);
  rowpass_kernel<<<dim3(N_PTR), 256, 0, stream>>>(
      S, G, ptr_lab, nu_lab, nloss, row_max, row_sum, s_sum, gy_sum);
  colpass_kernel<<<dim3(M_NU / 256, 16), 256, 0, stream>>>(
      S, G, ptr_lab, nu_lab, nloss, row_max, row_sum, partial);
  final_kernel<<<dim3(1), 256, 0, stream>>>(partial, nloss, s_sum, gy_sum, out);
}

// Round 2
// 109.458 us; speedup vs baseline: 2.3045x; 2.3045x over previous
//
#include <hip/hip_runtime.h>
#include <math.h>

#define N_PTR 2048
#define M_NU  4096
#define DIM   512
#define KCLS  1000
#define KPAD  1024

static constexpr float LAMBDA_ = 0.1f;
static constexpr float EPSILON_ = 0.5f;
static constexpr float EPS_ = 1e-8f;

typedef short short8 __attribute__((ext_vector_type(8)));
typedef unsigned short u16x8 __attribute__((ext_vector_type(8)));
typedef float f32x4 __attribute__((ext_vector_type(4)));

__device__ __forceinline__ unsigned short f2bf(float x) {
  unsigned u = __float_as_uint(x);
  u += 0x7fff + ((u >> 16) & 1);     // round-to-nearest-even
  return (unsigned short)(u >> 16);
}
__device__ __forceinline__ float bf2f(unsigned short h) {
  return __uint_as_float(((unsigned)h) << 16);
}

__device__ __forceinline__ void gload16(const void* g, void* l) {
  __builtin_amdgcn_global_load_lds(
      (const __attribute__((address_space(1))) unsigned int*)g,
      (__attribute__((address_space(3))) unsigned int*)l, 16, 0, 0);
}

// ---------- block reduction helpers (blockDim.x == 256) ----------
__device__ __forceinline__ float blk_reduce_sum(float v, float* red) {
  #pragma unroll
  for (int off = 32; off > 0; off >>= 1) v += __shfl_down(v, off);
  __syncthreads();
  if ((threadIdx.x & 63) == 0) red[threadIdx.x >> 6] = v;
  __syncthreads();
  return red[0] + red[1] + red[2] + red[3];
}

__device__ __forceinline__ float blk_reduce_max(float v, float* red) {
  #pragma unroll
  for (int off = 32; off > 0; off >>= 1) v = fmaxf(v, __shfl_down(v, off));
  __syncthreads();
  if ((threadIdx.x & 63) == 0) red[threadIdx.x >> 6] = v;
  __syncthreads();
  return fmaxf(fmaxf(red[0], red[1]), fmaxf(red[2], red[3]));
}

// ---------- 1. fused normalize + bf16 cast for all three matrices ----------
// one wave per row (512 f32 = 8/lane); cls padded to 1024 rows with zeros
__global__ __launch_bounds__(256) void normcast_kernel(
    const float* __restrict__ ptr_f, const float* __restrict__ nu_f,
    const float* __restrict__ cls_f, unsigned short* __restrict__ An,
    unsigned short* __restrict__ Bn, unsigned short* __restrict__ Cn) {
  int gid = blockIdx.x * 256 + threadIdx.x;
  int row = gid >> 6, lane = gid & 63;
  const float* src; unsigned short* dst; int lrow; int in_rows;
  if (row < N_PTR)               { src = ptr_f; dst = An; lrow = row;                 in_rows = N_PTR; }
  else if (row < N_PTR + M_NU)   { src = nu_f;  dst = Bn; lrow = row - N_PTR;         in_rows = M_NU; }
  else                           { src = cls_f; dst = Cn; lrow = row - N_PTR - M_NU;  in_rows = KCLS; }
  u16x8 ov;
  if (lrow < in_rows) {
    const float4* rp = (const float4*)(src + (size_t)lrow * DIM);
    float4 a = rp[lane * 2], b = rp[lane * 2 + 1];
    float v[8] = {a.x, a.y, a.z, a.w, b.x, b.y, b.z, b.w};
    float s = 0.f;
    #pragma unroll
    for (int j = 0; j < 8; ++j) s = fmaf(v[j], v[j], s);
    #pragma unroll
    for (int off = 32; off > 0; off >>= 1) s += __shfl_xor(s, off);
    float inv = 1.0f / fmaxf(sqrtf(s), EPS_);
    #pragma unroll
    for (int j = 0; j < 8; ++j) ov[j] = f2bf(v[j] * inv);
  } else {
    #pragma unroll
    for (int j = 0; j < 8; ++j) ov[j] = 0;
  }
  *(u16x8*)(dst + (size_t)lrow * DIM + lane * 8) = ov;
}

// ---------- 2. per-row CE loss (exact f32 — feeds 20x-amplified exponent) ----------
__global__ __launch_bounds__(256) void celoss_kernel(const float* __restrict__ logits,
                                                     const int* __restrict__ labels,
                                                     float* __restrict__ losses) {
  __shared__ float red[4];
  int row = blockIdx.x;
  int tid = threadIdx.x;
  const float* x = logits + (size_t)row * KCLS;
  float mx_loc = -INFINITY;
  for (int c = tid; c < KCLS; c += 256) mx_loc = fmaxf(mx_loc, x[c]);
  float mx = blk_reduce_max(mx_loc, red);
  float se_loc = 0.f;
  for (int c = tid; c < KCLS; c += 256) se_loc += expf(x[c] - mx);
  float se = blk_reduce_sum(se_loc, red);
  if (tid == 0) losses[row] = mx + logf(se) - x[labels[row]];
}

// ---------- 3. bf16 MFMA GEMM: C = A @ B^T (both row-major [rows][512]) ----------
// 128x128 tile, BK=64, 4 waves in 2x2, each wave 4x4 frags of 16x16x32.
// LDS linear [128][64] bf16, XOR-swizzled content (chunk ^= row&7) via per-lane
// pre-swizzled global source (global_load_lds dest is lane-linear).
template <int BF16_OUT>
__global__ __launch_bounds__(256) void mfma_gemm_nt(
    const unsigned short* __restrict__ A, const unsigned short* __restrict__ B,
    void* __restrict__ Cout, int ldc) {
  __shared__ unsigned short Alds[128 * 64];   // 16 KB
  __shared__ unsigned short Blds[128 * 64];   // 16 KB
  const int tid = threadIdx.x;
  const int w = tid >> 6, lane = tid & 63;
  const int brow = blockIdx.y * 128, bcol = blockIdx.x * 128;
  const int wr = w >> 1, wc = w & 1;

  const int sr = lane >> 3;        // row within 8-row staging group
  const int sc = lane & 7;         // 16B-chunk within 128B row
  const int schunk = (sc ^ sr) * 8;  // swizzled source element offset (row&7 == sr)

  f32x4 acc[4][4] = {};

  for (int k0 = 0; k0 < DIM; k0 += 64) {
    #pragma unroll
    for (int i = 0; i < 4; ++i) {
      int j = w * 4 + i;                 // staging instr 0..15, covers 8 rows each
      int r = j * 8 + sr;                // tile row this lane feeds
      gload16(A + (size_t)(brow + r) * DIM + k0 + schunk, (char*)Alds + j * 1024);
      gload16(B + (size_t)(bcol + r) * DIM + k0 + schunk, (char*)Blds + j * 1024);
    }
    __syncthreads();   // compiler drains vmcnt(0) before s_barrier

    #pragma unroll
    for (int kk = 0; kk < 2; ++kk) {
      const int koff = kk * 64 + (lane >> 4) * 16;   // logical byte offset in row
      short8 af[4], bfr[4];
      #pragma unroll
      for (int mi = 0; mi < 4; ++mi) {
        int r = wr * 64 + mi * 16 + (lane & 15);
        af[mi] = *(const short8*)((const char*)Alds + r * 128 + (koff ^ ((r & 7) << 4)));
      }
      #pragma unroll
      for (int ni = 0; ni < 4; ++ni) {
        int r = wc * 64 + ni * 16 + (lane & 15);
        bfr[ni] = *(const short8*)((const char*)Blds + r * 128 + (koff ^ ((r & 7) << 4)));
      }
      #pragma unroll
      for (int mi = 0; mi < 4; ++mi)
        #pragma unroll
        for (int ni = 0; ni < 4; ++ni)
          acc[mi][ni] = __builtin_amdgcn_mfma_f32_16x16x32_bf16(af[mi], bfr[ni], acc[mi][ni], 0, 0, 0);
    }
    __syncthreads();
  }

  // C/D layout: col = lane&15, row = (lane>>4)*4 + reg  [verified m89/m91]
  #pragma unroll
  for (int mi = 0; mi < 4; ++mi) {
    #pragma unroll
    for (int ni = 0; ni < 4; ++ni) {
      #pragma unroll
      for (int j = 0; j < 4; ++j) {
        int row = brow + wr * 64 + mi * 16 + (lane >> 4) * 4 + j;
        int col = bcol + wc * 64 + ni * 16 + (lane & 15);
        float vv = acc[mi][ni][j];
        if (BF16_OUT) ((unsigned short*)Cout)[(size_t)row * ldc + col] = f2bf(vv);
        else          ((float*)Cout)[(size_t)row * ldc + col] = vv;
      }
    }
  }
}

// ---------- 4. phase A: per-n row max / sumexp + cos-sum partials ----------
__global__ __launch_bounds__(256) void rowpass_kernel(const unsigned short* __restrict__ Sb,
    const float* __restrict__ G, const int* __restrict__ pl, const int* __restrict__ nl,
    const float* __restrict__ nu_loss, float* __restrict__ row_max,
    float* __restrict__ row_sum, float* __restrict__ s_sum, float* __restrict__ gy_sum) {
  __shared__ float e_row[M_NU];   // 16 KB
  __shared__ float red[4];
  int n = blockIdx.x;
  int tid = threadIdx.x;
  const unsigned short* Srow = Sb + (size_t)n * M_NU;
  const float* Grow = G + (size_t)pl[n] * KPAD;
  const float inv_denom = 1.0f / (LAMBDA_ * EPSILON_ + EPS_);
  float loc_s = 0.f, loc_gy = 0.f, loc_max = -INFINITY;
  for (int mb = tid * 8; mb < M_NU; mb += 2048) {
    u16x8 sv = *(const u16x8*)(Srow + mb);
    #pragma unroll
    for (int j = 0; j < 8; ++j) {
      int m = mb + j;
      float s = bf2f(sv[j]);
      float gy = Grow[nl[m]];
      float e = (nu_loss[m] - LAMBDA_ * ((1.f - s) + (1.f - gy))) * inv_denom;
      e_row[m] = e;
      loc_s += s; loc_gy += gy;
      loc_max = fmaxf(loc_max, e);
    }
  }
  float rmax = blk_reduce_max(loc_max, red);
  float loc_w = 0.f;
  for (int m = tid; m < M_NU; m += 256) loc_w += expf(e_row[m] - rmax);
  float wsum = blk_reduce_sum(loc_w, red);
  float stot = blk_reduce_sum(loc_s, red);
  float gtot = blk_reduce_sum(loc_gy, red);
  if (tid == 0) {
    row_max[n] = rmax;
    row_sum[n] = wsum;
    s_sum[n] = stot;
    gy_sum[n] = gtot;
  }
}

// ---------- 5. phase B: per-m column sums of weights (no atomics) ----------
__global__ __launch_bounds__(256) void colpass_kernel(const unsigned short* __restrict__ Sb,
    const float* __restrict__ G, const int* __restrict__ pl, const int* __restrict__ nl,
    const float* __restrict__ nu_loss, const float* __restrict__ row_max,
    const float* __restrict__ row_sum, float* __restrict__ partial) {
  int m = blockIdx.x * 256 + threadIdx.x;     // grid.x = M/256
  int chunk = blockIdx.y;                     // 16 chunks of 128 rows
  const int rows_per_chunk = N_PTR / 16;
  int n0 = chunk * rows_per_chunk;
  const float inv_denom = 1.0f / (LAMBDA_ * EPSILON_ + EPS_);
  int nlm = nl[m];
  float lm = nu_loss[m];
  float acc = 0.f;
  for (int n = n0; n < n0 + rows_per_chunk; ++n) {
    float s = bf2f(Sb[(size_t)n * M_NU + m]);
    float gy = G[(size_t)pl[n] * KPAD + nlm];
    float e = (lm - LAMBDA_ * ((1.f - s) + (1.f - gy))) * inv_denom;
    acc += expf(e - row_max[n]) / (row_sum[n] + EPS_);
  }
  partial[(size_t)chunk * M_NU + m] = acc;
}

// ---------- 6. finalize: probs, dro_loss, means ----------
__global__ __launch_bounds__(256) void final_kernel(const float* __restrict__ partial,
    const float* __restrict__ nu_loss, const float* __restrict__ s_sum,
    const float* __restrict__ gy_sum, float* __restrict__ out) {
  __shared__ float red[4];
  int tid = threadIdx.x;
  float locT = 0.f;
  for (int m = tid; m < M_NU; m += 256) {
    float t = 0.f;
    #pragma unroll
    for (int c = 0; c < 16; ++c) t += partial[(size_t)c * M_NU + m];
    out[2 + m] = t;            // raw sum over n, rescaled below
    locT += t;
  }
  float T = blk_reduce_sum(locT, red);
  float scale = (1.0f / (float)N_PTR) / (T / (float)N_PTR + EPS_);
  float locD = 0.f;
  for (int m = tid; m < M_NU; m += 256) {
    float p = out[2 + m] * scale;
    out[2 + m] = p;
    locD += p * nu_loss[m];
  }
  float dro = blk_reduce_sum(locD, red);
  float locS = 0.f, locG = 0.f;
  for (int n = tid; n < N_PTR; n += 256) { locS += s_sum[n]; locG += gy_sum[n]; }
  float Stot = blk_reduce_sum(locS, red);
  float Gtot = blk_reduce_sum(locG, red);
  if (tid == 0) {
    const float invNM = 1.0f / ((float)N_PTR * (float)M_NU);
    float mcx = 1.f - Stot * invNM;
    float mcy = 1.f - Gtot * invNM;
    out[0] = dro;              // total_loss (semantic part is 0)
    out[1] = dro;              // dro_loss
    out[2 + M_NU] = mcx + mcy; // mean(C_total)
    out[3 + M_NU] = mcx;       // mean(C_X)
    out[4 + M_NU] = mcy;       // mean(C_Y)
  }
}

extern "C" void kernel_launch(void* const* d_in, const int* in_sizes, int n_in,
                              void* d_out, int out_size, void* d_ws, size_t ws_size,
                              hipStream_t stream) {
  const float* ptr_feat = (const float*)d_in[0];
  // d_in[1] = ptr_logits: unused by the reference
  const int*   ptr_lab  = (const int*)d_in[2];
  const float* nu_feat  = (const float*)d_in[3];
  const float* nu_log   = (const float*)d_in[4];
  const int*   nu_lab   = (const int*)d_in[5];
  const float* cls_w    = (const float*)d_in[6];
  float* out = (float*)d_out;

  char* w0 = (char*)d_ws;
  unsigned short* Sb = (unsigned short*)w0;                                 // 16 MB
  float* G  = (float*)(w0 + (size_t)N_PTR * M_NU * 2);                      // 4 MB
  unsigned short* An = (unsigned short*)((char*)G + (size_t)KPAD * KPAD * 4); // 2 MB
  unsigned short* Bn = An + (size_t)N_PTR * DIM;                            // 4 MB
  unsigned short* Cn = Bn + (size_t)M_NU * DIM;                             // 1 MB
  float* nloss   = (float*)(Cn + (size_t)KPAD * DIM);
  float* row_max = nloss + M_NU;
  float* row_sum = row_max + N_PTR;
  float* s_sum   = row_sum + N_PTR;
  float* gy_sum  = s_sum + N_PTR;
  float* partial = gy_sum + N_PTR;   // 16 * M_NU

  const int total_rows = N_PTR + M_NU + KPAD;   // 7168
  normcast_kernel<<<dim3(total_rows / 4), 256, 0, stream>>>(ptr_feat, nu_feat, cls_w, An, Bn, Cn);
  celoss_kernel<<<dim3(M_NU), 256, 0, stream>>>(nu_log, nu_lab, nloss);
  mfma_gemm_nt<1><<<dim3(M_NU / 128, N_PTR / 128), 256, 0, stream>>>(An, Bn, Sb, M_NU);
  mfma_gemm_nt<0><<<dim3(KPAD / 128, KPAD / 128), 256, 0, stream>>>(Cn, Cn, G, KPAD);
  rowpass_kernel<<<dim3(N_PTR), 256, 0, stream>>>(Sb, G, ptr_lab, nu_lab, nloss,
                                                  row_max, row_sum, s_sum, gy_sum);
  colpass_kernel<<<dim3(M_NU / 256, 16), 256, 0, stream>>>(Sb, G, ptr_lab, nu_lab, nloss,
                                                           row_max, row_sum, partial);
  final_kernel<<<dim3(1), 256, 0, stream>>>(partial, nloss, s_sum, gy_sum, out);
}